// Round 2
// baseline (780.464 us; speedup 1.0000x reference)
//
#include <hip/hip_runtime.h>

// ---- problem constants ----
constexpr int DIM = 768;
constexpr int NH  = 12;
constexpr int HDm = 64;
constexpr int HALF = 32;
constexpr int LATm = 256;
constexpr int NB  = 16;
constexpr int SEQ = 8192;
constexpr int NPRIME = NH * DIM;      // 9216
constexpr int SSPLIT = 16;
constexpr int SRANGE = SEQ / SSPLIT;  // 512

typedef short bf16x8 __attribute__((ext_vector_type(8)));
typedef float f32x4  __attribute__((ext_vector_type(4)));
using u16 = unsigned short;

__device__ __forceinline__ u16 f2b(float f) {
    unsigned int u = __float_as_uint(f);
    u += 0x7FFFu + ((u >> 16) & 1u);   // RNE; inputs are finite
    return (u16)(u >> 16);
}
__device__ __forceinline__ float b2f(u16 u) {
    union { unsigned int i; float f; } v; v.i = ((unsigned int)u) << 16; return v.f;
}

// ---- generic batched matvec (all f32): vout[b,row] = W[row,:] . vin[b,(slice)] + bias[row]
__global__ __launch_bounds__(256) void k_mv(const float* __restrict__ Wb,
        const float* __restrict__ bias, const float* __restrict__ vin,
        float* __restrict__ vout,
        int rows, int batch, int in_bstride, int out_bstride, int headslice) {
    int w = threadIdx.x >> 6, lane = threadIdx.x & 63;
    int gw = blockIdx.x * 4 + w;
    if (gw >= rows * batch) return;
    int b = gw / rows, row = gw - b * rows;
    const float* vi = vin + (size_t)b * in_bstride + (headslice ? (row >> 6) * DIM : 0);
    const float* wr = Wb + (size_t)row * DIM;
    float acc = 0.f;
    #pragma unroll
    for (int c = 0; c < DIM / 64; ++c)
        acc += wr[c * 64 + lane] * vi[c * 64 + lane];
    #pragma unroll
    for (int off = 32; off > 0; off >>= 1) acc += __shfl_xor(acc, off, 64);
    if (lane == 0) vout[(size_t)b * out_bstride + row] = acc + bias[row];
}

// ---- fold q into Wk (RoPE cos/sin split), 1/sqrt(64) folded in. bf16 out.
// UWpT[n'][c], n' = h*768+d, c in [0,64): c<32 cos-component, else sin-component.
__global__ void k_uw(const float* __restrict__ q, const float* __restrict__ Wk,
                     u16* __restrict__ UWpT) {
    int tid = blockIdx.x * 256 + threadIdx.x;      // 9216*64 total
    int np = tid >> 6, c = tid & 63;
    int h = np / DIM, d = np - h * DIM;
    int j = c & 31;
    float q1 = q[h * HDm + j], q2 = q[h * HDm + HALF + j];
    float wa = Wk[(size_t)(h * HDm + j) * DIM + d];
    float wb = Wk[(size_t)(h * HDm + HALF + j) * DIM + d];
    float v = (c < HALF) ? (q1 * wa + q2 * wb) : (q2 * wa - q1 * wb);
    UWpT[(size_t)np * 64 + c] = f2b(v * 0.125f);
}

// ---- trig table T[s][c]: c<32 -> cos(s*f_j), else sin(s*f_j) ----
__global__ void k_T(u16* __restrict__ T) {
    int tid = blockIdx.x * 256 + threadIdx.x;      // 8192*64
    int s = tid >> 6, c = tid & 63;
    int j = c & 31;
    float f = expf(-(float)j * (9.210340372f / 32.f));  // 10000^(-j/32)
    float ang = (float)s * f;
    float v = (c < HALF) ? cosf(ang) : sinf(ang);
    T[tid] = f2b(v);
}

// ---- Ebias[s][h] = (R(-s)q_h).bk_h * scale  (exact f32 handling of bk) ----
__global__ void k_eb(const float* __restrict__ q, const float* __restrict__ bk,
                     float* __restrict__ Ebias) {
    int tid = blockIdx.x * 256 + threadIdx.x;      // 8192*12
    if (tid >= SEQ * NH) return;
    int s = tid / NH, h = tid - s * NH;
    float acc = 0.f;
    for (int j = 0; j < HALF; ++j) {
        float f = expf(-(float)j * (9.210340372f / 32.f));
        float sv, cv; sincosf((float)s * f, &sv, &cv);
        float b1 = bk[h * HDm + j], b2 = bk[h * HDm + HALF + j];
        float q1 = q[h * HDm + j], q2 = q[h * HDm + HALF + j];
        acc += cv * (q1 * b1 + q2 * b2) + sv * (q2 * b1 - q1 * b2);
    }
    Ebias[tid] = acc * 0.125f;
}

// ---- E_chunk = T[s0:s0+cur] @ UW : M=cur, N=9216, K=64 MFMA GEMM ----
__global__ void __launch_bounds__(256) k_E(const u16* __restrict__ T,
        const u16* __restrict__ UWpT, u16* __restrict__ E, int s0) {
    int lane = threadIdx.x & 63, wid = threadIdx.x >> 6;
    int m0 = blockIdx.y * 128 + (wid >> 1) * 64;          // local row in chunk
    int n0 = blockIdx.x * 128 + (wid & 1) * 64;
    int l15 = lane & 15, quad = lane >> 4;
    f32x4 acc[4][4] = {};
    #pragma unroll
    for (int kq = 0; kq < 2; ++kq) {
        int kb = kq * 32 + quad * 8;
        bf16x8 a[4], b[4];
        #pragma unroll
        for (int i = 0; i < 4; ++i)
            a[i] = *(const bf16x8*)(T + (size_t)(s0 + m0 + i * 16 + l15) * 64 + kb);
        #pragma unroll
        for (int i = 0; i < 4; ++i)
            b[i] = *(const bf16x8*)(UWpT + (size_t)(n0 + i * 16 + l15) * 64 + kb);
        #pragma unroll
        for (int mi = 0; mi < 4; ++mi)
            #pragma unroll
            for (int ni = 0; ni < 4; ++ni)
                acc[mi][ni] = __builtin_amdgcn_mfma_f32_16x16x32_bf16(a[mi], b[ni], acc[mi][ni], 0, 0, 0);
    }
    #pragma unroll
    for (int mi = 0; mi < 4; ++mi)
        #pragma unroll
        for (int ni = 0; ni < 4; ++ni) {
            int col = n0 + ni * 16 + l15;
            #pragma unroll
            for (int r = 0; r < 4; ++r) {
                int row = m0 + mi * 16 + quad * 4 + r;
                E[(size_t)row * NPRIME + col] = f2b(acc[mi][ni][r]);
            }
        }
}

// ---- scores[b,h,s] = x[b,s,:] . E[s-s0,h,:] ; one wave per s.
// A: m=b(16), k=d (x f32 -> bf16 in-reg); B: k=d, n=h (h>=12 lanes read slack, discarded)
__global__ void __launch_bounds__(256) k_sc(const float* __restrict__ x,
        const u16* __restrict__ E, const float* __restrict__ Ebias,
        float* __restrict__ scores, int s0) {
    int lane = threadIdx.x & 63, wid = threadIdx.x >> 6;
    int sl = blockIdx.x * 4 + wid;
    int s = s0 + sl;
    int l15 = lane & 15, quad = lane >> 4;
    f32x4 acc = {};
    const float* xb = x + (size_t)l15 * SEQ * DIM + (size_t)s * DIM + quad * 8;  // b = l15
    const u16* eb = E + (size_t)sl * NPRIME + (size_t)l15 * DIM + quad * 8;      // h = l15
    #pragma unroll 4
    for (int kc = 0; kc < DIM / 32; ++kc) {
        float4 fa = *(const float4*)(xb + kc * 32);
        float4 fb = *(const float4*)(xb + kc * 32 + 4);
        bf16x8 av;
        av[0] = (short)f2b(fa.x); av[1] = (short)f2b(fa.y);
        av[2] = (short)f2b(fa.z); av[3] = (short)f2b(fa.w);
        av[4] = (short)f2b(fb.x); av[5] = (short)f2b(fb.y);
        av[6] = (short)f2b(fb.z); av[7] = (short)f2b(fb.w);
        bf16x8 bv = *(const bf16x8*)(eb + kc * 32);
        acc = __builtin_amdgcn_mfma_f32_16x16x32_bf16(av, bv, acc, 0, 0, 0);
    }
    int h = l15;
    if (h < NH) {
        float bias = Ebias[s * NH + h] - exp2f(-8.f * (h + 1) / 12.f) * (float)s;
        #pragma unroll
        for (int r = 0; r < 4; ++r) {
            int b = quad * 4 + r;
            scores[((size_t)b * NH + h) * SEQ + s] = acc[r] + bias;
        }
    }
}

// ---- softmax over s per (b,h) row, IN PLACE ----
__global__ void __launch_bounds__(256) k_sm(float* __restrict__ scores) {
    __shared__ float red[256];
    float* row = scores + (size_t)blockIdx.x * SEQ;
    int t = threadIdx.x;
    float m = -1e30f;
    for (int i = t; i < SEQ; i += 256) m = fmaxf(m, row[i]);
    red[t] = m; __syncthreads();
    for (int o = 128; o > 0; o >>= 1) { if (t < o) red[t] = fmaxf(red[t], red[t + o]); __syncthreads(); }
    m = red[0]; __syncthreads();
    float sum = 0.f;
    for (int i = t; i < SEQ; i += 256) sum += expf(row[i] - m);
    red[t] = sum; __syncthreads();
    for (int o = 128; o > 0; o >>= 1) { if (t < o) red[t] += red[t + o]; __syncthreads(); }
    float inv = 1.f / red[0];
    for (int i = t; i < SEQ; i += 256) row[i] = expf(row[i] - m) * inv;  // element-private: safe in place
}

// ---- pooled_x partials: part[sp][b][h][d] = sum_{s in chunk} attn[b,h,s]*x[b,s,d] ----
__global__ void __launch_bounds__(256) k_pool(const float* __restrict__ x,
        const float* __restrict__ attn, float* __restrict__ part) {
    __shared__ float lds[12288];                 // phase1: attn[12][512]; phase2: reduce
    int bx = blockIdx.x;                          // 16 sp * 16 b * 3 dc
    int sp = bx / 48, rem = bx % 48, b = rem / 3, dc = rem % 3;
    int s0 = sp * SRANGE, d0 = dc * 256;
    int t = threadIdx.x, dthr = t & 63, stripe = t >> 6;
    for (int i = t; i < NH * SRANGE; i += 256) {
        int h = i >> 9, si = i & 511;
        lds[i] = attn[((size_t)b * NH + h) * SEQ + s0 + si];
    }
    __syncthreads();
    float acc[NH][4] = {};
    const float* xp = x + ((size_t)b * SEQ + s0) * DIM + d0 + dthr * 4;
    for (int it = stripe * 128; it < stripe * 128 + 128; ++it) {
        float4 xv = *(const float4*)(xp + (size_t)it * DIM);
        #pragma unroll
        for (int h = 0; h < NH; ++h) {
            float a = lds[h * SRANGE + it];
            acc[h][0] += a * xv.x; acc[h][1] += a * xv.y;
            acc[h][2] += a * xv.z; acc[h][3] += a * xv.w;
        }
    }
    __syncthreads();
    #pragma unroll
    for (int h = 0; h < NH; ++h) {
        float* rp = lds + ((h * 4 + stripe) * 64 + dthr) * 4;
        rp[0] = acc[h][0]; rp[1] = acc[h][1]; rp[2] = acc[h][2]; rp[3] = acc[h][3];
    }
    __syncthreads();
    float* pb = part + (size_t)sp * (NB * NH * DIM) + (size_t)b * NH * DIM + d0;
    for (int i = t; i < NH * 64; i += 256) {
        int h = i >> 6, dt = i & 63;
        float4 v; v.x = v.y = v.z = v.w = 0.f;
        #pragma unroll
        for (int st = 0; st < 4; ++st) {
            const float* rp = lds + ((h * 4 + st) * 64 + dt) * 4;
            v.x += rp[0]; v.y += rp[1]; v.z += rp[2]; v.w += rp[3];
        }
        *(float4*)(pb + (size_t)h * DIM + dt * 4) = v;
    }
}

__global__ void k_red(const float* __restrict__ part, float* __restrict__ pooled) {
    int i = blockIdx.x * 256 + threadIdx.x;
    if (i < NB * NH * DIM) {
        float s = 0.f;
        for (int sp = 0; sp < SSPLIT; ++sp) s += part[(size_t)sp * (NB * NH * DIM) + i];
        pooled[i] = s;
    }
}

extern "C" void kernel_launch(void* const* d_in, const int* in_sizes, int n_in,
                              void* d_out, int out_size, void* d_ws, size_t ws_size,
                              hipStream_t stream) {
    (void)in_sizes; (void)n_in; (void)out_size;
    const float* x    = (const float*)d_in[0];
    const float* pool = (const float*)d_in[1];
    const float* Wq   = (const float*)d_in[2];
    const float* bq   = (const float*)d_in[3];
    const float* Wk   = (const float*)d_in[4];
    const float* bk   = (const float*)d_in[5];
    const float* Wv   = (const float*)d_in[6];
    const float* bv   = (const float*)d_in[7];
    const float* Wo   = (const float*)d_in[8];
    const float* bo   = (const float*)d_in[9];
    const float* Wl   = (const float*)d_in[10];
    const float* bl   = (const float*)d_in[11];

    char* w = (char*)d_ws;
    auto alloc = [&](size_t bytes) { char* p = w; w += (bytes + 255) & ~(size_t)255; return p; };
    float* q_f    = (float*)alloc(DIM * 4);
    u16*   UWpT   = (u16*)alloc((size_t)NPRIME * 64 * 2);
    u16*   Tt     = (u16*)alloc((size_t)SEQ * 64 * 2);
    float* Ebias  = (float*)alloc((size_t)SEQ * NH * 4);
    float* scores = (float*)alloc((size_t)NB * NH * SEQ * 4);   // softmax in-place -> attn
    float* part   = (float*)alloc((size_t)SSPLIT * NB * NH * DIM * 4);
    float* pooled = (float*)alloc((size_t)NB * NH * DIM * 4);
    float* o_buf  = (float*)alloc((size_t)NB * DIM * 4);
    float* p_buf  = (float*)alloc((size_t)NB * DIM * 4);

    // adaptive E chunk: as many s-rows of E (bf16, NPRIME wide) as ws allows
    size_t fixed_used = (size_t)(w - (char*)d_ws);
    size_t margin = 65536;  // covers k_sc h>=12 slack overread + alignment
    size_t avail = (ws_size > fixed_used + margin) ? (ws_size - fixed_used - margin) : 0;
    size_t rows = avail / ((size_t)NPRIME * 2);
    int chunk = (rows >= (size_t)SEQ) ? SEQ : (int)(rows & ~(size_t)127);
    if (chunk < 128) chunk = 128;
    u16* E = (u16*)alloc((size_t)chunk * NPRIME * 2 + 8192);

    hipLaunchKernelGGL(k_mv, dim3(192), dim3(256), 0, stream,
                       Wq, bq, pool, q_f, DIM, 1, 0, DIM, 0);
    hipLaunchKernelGGL(k_uw, dim3(NPRIME * 64 / 256), dim3(256), 0, stream, q_f, Wk, UWpT);
    hipLaunchKernelGGL(k_T, dim3(SEQ * 64 / 256), dim3(256), 0, stream, Tt);
    hipLaunchKernelGGL(k_eb, dim3((SEQ * NH + 255) / 256), dim3(256), 0, stream, q_f, bk, Ebias);
    for (int s0 = 0; s0 < SEQ; s0 += chunk) {
        int cur = (SEQ - s0 < chunk) ? (SEQ - s0) : chunk;   // multiple of 128
        hipLaunchKernelGGL(k_E, dim3(NPRIME / 128, cur / 128), dim3(256), 0, stream,
                           Tt, UWpT, E, s0);
        hipLaunchKernelGGL(k_sc, dim3(cur / 4), dim3(256), 0, stream,
                           x, E, Ebias, scores, s0);
    }
    hipLaunchKernelGGL(k_sm, dim3(NB * NH), dim3(256), 0, stream, scores);
    hipLaunchKernelGGL(k_pool, dim3(SSPLIT * NB * 3), dim3(256), 0, stream, x, scores, part);
    hipLaunchKernelGGL(k_red, dim3((NB * NH * DIM + 255) / 256), dim3(256), 0, stream, part, pooled);
    hipLaunchKernelGGL(k_mv, dim3(NB * DIM / 4), dim3(256), 0, stream,
                       Wv, bv, pooled, o_buf, DIM, NB, NH * DIM, DIM, 1);
    hipLaunchKernelGGL(k_mv, dim3(NB * DIM / 4), dim3(256), 0, stream,
                       Wo, bo, o_buf, p_buf, DIM, NB, DIM, DIM, 0);
    hipLaunchKernelGGL(k_mv, dim3(NB * LATm / 4), dim3(256), 0, stream,
                       Wl, bl, p_buf, (float*)d_out, LATm, NB, DIM, LATm, 0);
}